// Round 6
// baseline (49.029 us; speedup 1.0000x reference)
//
#include <hip/hip_runtime.h>

// FFD cubic B-spline flow generation, separable (x -> y -> z).
// mesh: [4][3][23][27][23] f32, out: [4][3][160][192][160] f32, spacing 8 all axes.
// d = (i&7)/8 (8 weight rows shared by all axes), pivot = i>>3.
//
// LDS intermediates keyed [cz][...] so flat indices decompose with shifts only:
//   tX  [cz][x8][b2]      stride 32 words  (23*32 = 736 outputs, stage A)
//   tXY [cz][x8*8+y8]     stride 72 words  (23*64 = 1472 outputs, stage B;
//                          72%32==8 -> stage C reads hit all 32 banks once)
// Stage C: 8 lanes per output row -> each store inst writes a full 128B line;
// non-temporal (streaming) stores bypass L2 allocation for the write-once output.

#define SPX 160
#define SPY 192
#define SPZ 160
#define CPX 23
#define CPY 27
#define CPZ 23

#define TXS  32   // tX  cz-stride (words)
#define TXYS 72   // tXY cz-stride (words), 72 mod 32 = 8

typedef float vfloat4 __attribute__((ext_vector_type(4)));

__global__ __launch_bounds__(256, 8) void ffd_kernel(const float* __restrict__ mesh,
                                                     float* __restrict__ out) {
    const int yb  = blockIdx.x;   // 0..23  (y block of 8)
    const int xb  = blockIdx.y;   // 0..19  (x block of 8)
    const int bc  = blockIdx.z;   // 0..11  (b*3 + c)
    const int tid = threadIdx.x;

    __shared__ __align__(16) float wlds[8][4];
    __shared__ __align__(16) float tX[CPZ * TXS];
    __shared__ __align__(16) float tXY[CPZ * TXYS];

    // cubic B-spline weight table for the 8 fractional offsets
    if (tid < 32) {
        int j = tid >> 2, a = tid & 3;
        float d  = (float)j * 0.125f;
        float d2 = d * d, d3 = d2 * d;
        float w;
        if (a == 0)      { float e = 1.0f - d; w = e * e * e * (1.0f / 6.0f); }
        else if (a == 1) { w = 0.5f * d3 - d2 + (2.0f / 3.0f); }
        else if (a == 2) { w = -0.5f * d3 + 0.5f * d2 + 0.5f * d + (1.0f / 6.0f); }
        else             { w = d3 * (1.0f / 6.0f); }
        wlds[j][a] = w;
    }
    __syncthreads();

    // stage A: contract x from global (mesh is L2-resident).
    // i = cz*32 + x8*4 + b2 ; tX[cz][x8][b2] = sum_a wlds[x8][a]*mesh[xb+a][yb+b2][cz]
    const float* mbase = mesh + (size_t)bc * (CPX * CPY * CPZ)
                              + (size_t)xb * (CPY * CPZ) + (size_t)yb * CPZ;
    #pragma unroll
    for (int j = 0; j < 3; ++j) {
        int i = tid + 256 * j;
        if (j < 2 || tid < 736 - 512) {
            int b2 = i & 3, x8 = (i >> 2) & 7, cz = i >> 5;
            const float* mp = mbase + b2 * CPZ + cz;
            float acc = wlds[x8][0] * mp[0]
                      + wlds[x8][1] * mp[CPY * CPZ]
                      + wlds[x8][2] * mp[2 * CPY * CPZ]
                      + wlds[x8][3] * mp[3 * CPY * CPZ];
            tX[cz * TXS + x8 * 4 + b2] = acc;
        }
    }
    __syncthreads();

    // stage B: contract y.
    // i = cz*64 + x8*8 + y8 ; tXY[cz][x8*8+y8] = sum_b2 wlds[y8][b2]*tX[cz][x8][b2]
    #pragma unroll
    for (int j = 0; j < 6; ++j) {
        int i = tid + 256 * j;
        if (j < 5 || tid < 1472 - 1280) {
            int y8 = i & 7, x8 = (i >> 3) & 7, cz = i >> 6;
            const float4 t4 = *(const float4*)&tX[cz * TXS + x8 * 4];  // broadcast b128
            float acc = wlds[y8][0] * t4.x + wlds[y8][1] * t4.y
                      + wlds[y8][2] * t4.z + wlds[y8][3] * t4.w;
            tXY[cz * TXYS + x8 * 8 + y8] = acc;
        }
    }
    __syncthreads();

    // stage C: expand z and store. 8 lanes per (x8,y8) row, 2 rows per thread.
    // out z = 32k + 4*zt + e' -> q = 4k + (zt>>1), W rows 4*(zt&1)..+3.
    const int zt = tid & 7;
    const int h  = zt & 1;
    const int qo = zt >> 1;
    const float4 Wr0 = *(const float4*)&wlds[4 * h + 0][0];
    const float4 Wr1 = *(const float4*)&wlds[4 * h + 1][0];
    const float4 Wr2 = *(const float4*)&wlds[4 * h + 2][0];
    const float4 Wr3 = *(const float4*)&wlds[4 * h + 3][0];

    float* oblk = out + ((size_t)bc * SPX * SPY
                       + (size_t)(xb * 8) * SPY
                       + (size_t)(yb * 8)) * SPZ;
    #pragma unroll
    for (int pass = 0; pass < 2; ++pass) {
        int row = pass * 32 + (tid >> 3);   // 0..63; per wave: one x8, y8=0..7
        int x8 = row >> 3, y8 = row & 7;
        const float* tcol = &tXY[x8 * 8 + y8];
        float* orow = oblk + ((size_t)x8 * SPY + (size_t)y8) * SPZ;
        #pragma unroll
        for (int k = 0; k < 5; ++k) {
            int qa = 4 * k + qo;
            float m0 = tcol[qa * TXYS];
            float m1 = tcol[(qa + 1) * TXYS];
            float m2 = tcol[(qa + 2) * TXYS];
            float m3 = tcol[(qa + 3) * TXYS];
            vfloat4 o;
            o.x = Wr0.x * m0 + Wr0.y * m1 + Wr0.z * m2 + Wr0.w * m3;
            o.y = Wr1.x * m0 + Wr1.y * m1 + Wr1.z * m2 + Wr1.w * m3;
            o.z = Wr2.x * m0 + Wr2.y * m1 + Wr2.z * m2 + Wr2.w * m3;
            o.w = Wr3.x * m0 + Wr3.y * m1 + Wr3.z * m2 + Wr3.w * m3;
            __builtin_nontemporal_store(o, (vfloat4*)&orow[32 * k + 4 * zt]);
        }
    }
}

extern "C" void kernel_launch(void* const* d_in, const int* in_sizes, int n_in,
                              void* d_out, int out_size, void* d_ws, size_t ws_size,
                              hipStream_t stream) {
    const float* mesh = (const float*)d_in[0];
    float* out = (float*)d_out;
    dim3 grid(SPY / 8, SPX / 8, 4 * 3);   // (24, 20, 12) = 5760 blocks
    ffd_kernel<<<grid, 256, 0, stream>>>(mesh, out);
}

// Round 7
// 41.924 us; speedup vs baseline: 1.1695x; 1.1695x over previous
//
#include <hip/hip_runtime.h>

// FFD cubic B-spline flow generation, separable (x -> y -> z).
// mesh: [4][3][23][27][23] f32, out: [4][3][160][192][160] f32, spacing 8 all axes.
// d = (i&7)/8 (8 weight rows shared by all axes), pivot = i>>3.
//
// LDS intermediates keyed [cz][...] so flat indices decompose with shifts only:
//   tX  [cz][x8][b2]      stride 32 words  (23*32 = 736 outputs, stage A)
//   tXY [cz][x8*8+y8]     stride 72 words  (23*64 = 1472 outputs, stage B;
//                          72%32==8 -> stage C reads hit all 32 banks, 2-way broadcast)
// Stage C: 8 lanes per output row -> each store inst writes a full 128B line.
// (R6 lesson: non-temporal stores REGRESSED 42.6->49.0 us — L2 write allocation
//  is part of the fast store path on MI355X. Plain stores here.)

#define SPX 160
#define SPY 192
#define SPZ 160
#define CPX 23
#define CPY 27
#define CPZ 23

#define TXS  32   // tX  cz-stride (words)
#define TXYS 72   // tXY cz-stride (words), 72 mod 32 = 8

__global__ __launch_bounds__(256, 8) void ffd_kernel(const float* __restrict__ mesh,
                                                     float* __restrict__ out) {
    const int yb  = blockIdx.x;   // 0..23  (y block of 8)
    const int xb  = blockIdx.y;   // 0..19  (x block of 8)
    const int bc  = blockIdx.z;   // 0..11  (b*3 + c)
    const int tid = threadIdx.x;

    __shared__ __align__(16) float wlds[8][4];
    __shared__ __align__(16) float tX[CPZ * TXS];
    __shared__ __align__(16) float tXY[CPZ * TXYS];

    // cubic B-spline weight table for the 8 fractional offsets
    if (tid < 32) {
        int j = tid >> 2, a = tid & 3;
        float d  = (float)j * 0.125f;
        float d2 = d * d, d3 = d2 * d;
        float w;
        if (a == 0)      { float e = 1.0f - d; w = e * e * e * (1.0f / 6.0f); }
        else if (a == 1) { w = 0.5f * d3 - d2 + (2.0f / 3.0f); }
        else if (a == 2) { w = -0.5f * d3 + 0.5f * d2 + 0.5f * d + (1.0f / 6.0f); }
        else             { w = d3 * (1.0f / 6.0f); }
        wlds[j][a] = w;
    }
    __syncthreads();

    // stage A: contract x from global (mesh is L2-resident).
    // i = cz*32 + x8*4 + b2 ; tX[cz][x8][b2] = sum_a wlds[x8][a]*mesh[xb+a][yb+b2][cz]
    const float* mbase = mesh + (size_t)bc * (CPX * CPY * CPZ)
                              + (size_t)xb * (CPY * CPZ) + (size_t)yb * CPZ;
    #pragma unroll
    for (int j = 0; j < 3; ++j) {
        int i = tid + 256 * j;
        if (j < 2 || tid < 736 - 512) {
            int b2 = i & 3, x8 = (i >> 2) & 7, cz = i >> 5;
            const float* mp = mbase + b2 * CPZ + cz;
            float acc = wlds[x8][0] * mp[0]
                      + wlds[x8][1] * mp[CPY * CPZ]
                      + wlds[x8][2] * mp[2 * CPY * CPZ]
                      + wlds[x8][3] * mp[3 * CPY * CPZ];
            tX[cz * TXS + x8 * 4 + b2] = acc;
        }
    }
    __syncthreads();

    // stage B: contract y.
    // i = cz*64 + x8*8 + y8 ; tXY[cz][x8*8+y8] = sum_b2 wlds[y8][b2]*tX[cz][x8][b2]
    #pragma unroll
    for (int j = 0; j < 6; ++j) {
        int i = tid + 256 * j;
        if (j < 5 || tid < 1472 - 1280) {
            int y8 = i & 7, x8 = (i >> 3) & 7, cz = i >> 6;
            const float4 t4 = *(const float4*)&tX[cz * TXS + x8 * 4];  // broadcast b128
            float acc = wlds[y8][0] * t4.x + wlds[y8][1] * t4.y
                      + wlds[y8][2] * t4.z + wlds[y8][3] * t4.w;
            tXY[cz * TXYS + x8 * 8 + y8] = acc;
        }
    }
    __syncthreads();

    // stage C: expand z and store. 8 lanes per (x8,y8) row, 2 rows per thread.
    // out z = 32k + 4*zt + e' -> q = 4k + (zt>>1), W rows 4*(zt&1)..+3.
    const int zt = tid & 7;
    const int h  = zt & 1;
    const int qo = zt >> 1;
    const float4 Wr0 = *(const float4*)&wlds[4 * h + 0][0];
    const float4 Wr1 = *(const float4*)&wlds[4 * h + 1][0];
    const float4 Wr2 = *(const float4*)&wlds[4 * h + 2][0];
    const float4 Wr3 = *(const float4*)&wlds[4 * h + 3][0];

    float* oblk = out + ((size_t)bc * SPX * SPY
                       + (size_t)(xb * 8) * SPY
                       + (size_t)(yb * 8)) * SPZ;
    #pragma unroll
    for (int pass = 0; pass < 2; ++pass) {
        int row = pass * 32 + (tid >> 3);   // 0..63; per wave: one x8, y8=0..7
        int x8 = row >> 3, y8 = row & 7;
        const float* tcol = &tXY[x8 * 8 + y8];
        float* orow = oblk + ((size_t)x8 * SPY + (size_t)y8) * SPZ;
        #pragma unroll
        for (int k = 0; k < 5; ++k) {
            int qa = 4 * k + qo;
            float m0 = tcol[qa * TXYS];
            float m1 = tcol[(qa + 1) * TXYS];
            float m2 = tcol[(qa + 2) * TXYS];
            float m3 = tcol[(qa + 3) * TXYS];
            float4 o;
            o.x = Wr0.x * m0 + Wr0.y * m1 + Wr0.z * m2 + Wr0.w * m3;
            o.y = Wr1.x * m0 + Wr1.y * m1 + Wr1.z * m2 + Wr1.w * m3;
            o.z = Wr2.x * m0 + Wr2.y * m1 + Wr2.z * m2 + Wr2.w * m3;
            o.w = Wr3.x * m0 + Wr3.y * m1 + Wr3.z * m2 + Wr3.w * m3;
            *(float4*)&orow[32 * k + 4 * zt] = o;
        }
    }
}

extern "C" void kernel_launch(void* const* d_in, const int* in_sizes, int n_in,
                              void* d_out, int out_size, void* d_ws, size_t ws_size,
                              hipStream_t stream) {
    const float* mesh = (const float*)d_in[0];
    float* out = (float*)d_out;
    dim3 grid(SPY / 8, SPX / 8, 4 * 3);   // (24, 20, 12) = 5760 blocks
    ffd_kernel<<<grid, 256, 0, stream>>>(mesh, out);
}

// Round 8
// 41.562 us; speedup vs baseline: 1.1796x; 1.0087x over previous
//
#include <hip/hip_runtime.h>

// FFD cubic B-spline flow generation, separable (x -> y -> z), BARRIER-FREE:
// each wave owns 2 x8-rows end-to-end with wave-private LDS; the only sync is
// s_waitcnt lgkmcnt(0) within the wave. No s_barrier anywhere -> waves drift
// under store back-pressure and keep the CU store stream fed.
//
// mesh: [4][3][23][27][23] f32, out: [4][3][160][192][160] f32, spacing 8 all
// axes -> d=(i&7)/8 (8 weight rows shared by all axes), pivot = i>>3.
// (R6 lesson: non-temporal stores regress badly — plain stores only.)

#define SPX 160
#define SPY 192
#define SPZ 160
#define CPX 23
#define CPY 27
#define CPZ 23
#define MXS (CPY * CPZ)   // 621, mesh x-plane stride

// wave-local LDS sync: all prior DS ops retired -> data visible to this wave
#define WAVE_LDS_SYNC() asm volatile("s_waitcnt lgkmcnt(0)" ::: "memory")

__global__ __launch_bounds__(256, 8) void ffd_kernel(const float* __restrict__ mesh,
                                                     float* __restrict__ out) {
    const int yb   = blockIdx.x;   // 0..23  (y block of 8)
    const int xb   = blockIdx.y;   // 0..19  (x block of 8)
    const int bc   = blockIdx.z;   // 0..11  (b*3 + c)
    const int tid  = threadIdx.x;
    const int lane = tid & 63;
    const int wid  = tid >> 6;     // 0..3, wave owns x8 = 2*wid + {0,1}

    __shared__ __align__(16) float wlds[8][4];
    __shared__ __align__(16) float tXw[4][2][24][4];   // [wave][xh][cz][b2]
    __shared__ __align__(16) float tXYw[4][2][8][24];  // [wave][xh][y8][cz]

    // weight table: every wave writes the same 32 values (idempotent, no barrier)
    if (lane < 32) {
        int j = lane >> 2, a = lane & 3;
        float d  = (float)j * 0.125f;
        float d2 = d * d, d3 = d2 * d;
        float w;
        if (a == 0)      { float e = 1.0f - d; w = e * e * e * (1.0f / 6.0f); }
        else if (a == 1) { w = 0.5f * d3 - d2 + (2.0f / 3.0f); }
        else if (a == 2) { w = -0.5f * d3 + 0.5f * d2 + 0.5f * d + (1.0f / 6.0f); }
        else             { w = d3 * (1.0f / 6.0f); }
        wlds[j][a] = w;
    }
    WAVE_LDS_SYNC();

    // stage A: contract x from global (mesh is L2-resident), 184 values/wave.
    // i = cz*8 + xh*4 + b2 ; tX[xh][cz][b2] = sum_a wlds[2w+xh][a]*mesh[xb+a][yb+b2][cz]
    const float* mbase = mesh + (size_t)bc * (CPX * CPY * CPZ)
                              + (size_t)xb * MXS + (size_t)yb * CPZ;
    #pragma unroll
    for (int j = 0; j < 3; ++j) {
        int i = lane + 64 * j;
        if (j < 2 || lane < 184 - 128) {
            int b2 = i & 3, xh = (i >> 2) & 1, cz = i >> 3;
            const float4 wr = *(const float4*)&wlds[2 * wid + xh][0];
            const float* mp = mbase + b2 * CPZ + cz;
            float acc = wr.x * mp[0]
                      + wr.y * mp[MXS]
                      + wr.z * mp[2 * MXS]
                      + wr.w * mp[3 * MXS];
            tXw[wid][xh][cz][b2] = acc;
        }
    }
    WAVE_LDS_SYNC();

    // stage B: contract y, 368 values/wave.
    // i = cz*16 + xh*8 + y8 ; tXY[xh][y8][cz] = dot(wlds[y8], tX[xh][cz])
    #pragma unroll
    for (int j = 0; j < 6; ++j) {
        int i = lane + 64 * j;
        if (j < 5 || lane < 368 - 320) {
            int y8 = i & 7, xh = (i >> 3) & 1, cz = i >> 4;
            const float4 wr = *(const float4*)&wlds[y8][0];
            const float4 t4 = *(const float4*)&tXw[wid][xh][cz][0];
            tXYw[wid][xh][y8][cz] = wr.x * t4.x + wr.y * t4.y
                                  + wr.z * t4.z + wr.w * t4.w;
        }
    }
    WAVE_LDS_SYNC();

    // stage C: expand z + store. lane = (y8, zt); per xh: 5 full-line float4 stores.
    // out z = 32k + 4*zt + e' -> q = 4k + (zt>>1), W rows 4*(zt&1)..+3.
    const int zt = lane & 7;
    const int y8 = lane >> 3;
    const int h  = zt & 1;
    const int qo = zt >> 1;
    const float4 Wr0 = *(const float4*)&wlds[4 * h + 0][0];
    const float4 Wr1 = *(const float4*)&wlds[4 * h + 1][0];
    const float4 Wr2 = *(const float4*)&wlds[4 * h + 2][0];
    const float4 Wr3 = *(const float4*)&wlds[4 * h + 3][0];

    float* oblk = out + ((size_t)bc * SPX * SPY
                       + (size_t)(xb * 8) * SPY
                       + (size_t)(yb * 8)) * SPZ;
    #pragma unroll
    for (int xh = 0; xh < 2; ++xh) {
        int x8 = 2 * wid + xh;
        const float* tcol = &tXYw[wid][xh][y8][0];
        float* orow = oblk + ((size_t)x8 * SPY + (size_t)y8) * SPZ;
        #pragma unroll
        for (int k = 0; k < 5; ++k) {
            int qa = 4 * k + qo;
            float m0 = tcol[qa];
            float m1 = tcol[qa + 1];
            float m2 = tcol[qa + 2];
            float m3 = tcol[qa + 3];
            float4 o;
            o.x = Wr0.x * m0 + Wr0.y * m1 + Wr0.z * m2 + Wr0.w * m3;
            o.y = Wr1.x * m0 + Wr1.y * m1 + Wr1.z * m2 + Wr1.w * m3;
            o.z = Wr2.x * m0 + Wr2.y * m1 + Wr2.z * m2 + Wr2.w * m3;
            o.w = Wr3.x * m0 + Wr3.y * m1 + Wr3.z * m2 + Wr3.w * m3;
            *(float4*)&orow[32 * k + 4 * zt] = o;
        }
    }
}

extern "C" void kernel_launch(void* const* d_in, const int* in_sizes, int n_in,
                              void* d_out, int out_size, void* d_ws, size_t ws_size,
                              hipStream_t stream) {
    const float* mesh = (const float*)d_in[0];
    float* out = (float*)d_out;
    dim3 grid(SPY / 8, SPX / 8, 4 * 3);   // (24, 20, 12) = 5760 blocks
    ffd_kernel<<<grid, 256, 0, stream>>>(mesh, out);
}